// Round 4
// baseline (147.942 us; speedup 1.0000x reference)
//
#include <hip/hip_runtime.h>

#define NN 8192
#define TT 1024
#define WW 64
#define HH 256
#define NPB 8
#define CHUNK 256
#define DTF (1.0f/24.0f)

__device__ __forceinline__ float sigmoidf_(float v) { return 1.0f / (1.0f + __expf(-v)); }

// ---------------- MLP -> (k, xw) -> IRF[n][64] in ws ----------------
__global__ __launch_bounds__(256) void mlp_kernel(
    const float* __restrict__ phys,
    const float* __restrict__ w1, const float* __restrict__ b1,
    const float* __restrict__ w2, const float* __restrict__ b2,
    const float* __restrict__ w3, const float* __restrict__ b3,
    float* __restrict__ irf)
{
    const int n0 = blockIdx.x * NPB;
    const int j  = threadIdx.x;

    __shared__ float s_phys[NPB * 3];
    __shared__ __align__(16) float s_h1[NPB * HH];   // 8 KB
    __shared__ float s_red[4][NPB][2];
    __shared__ float s_kxw[NPB][2];

    if (j < NPB * 3) s_phys[j] = phys[n0 * 3 + j];
    __syncthreads();

    // layer 1
    const float w1v0 = w1[j], w1v1 = w1[HH + j], w1v2 = w1[2 * HH + j], b1v = b1[j];
#pragma unroll
    for (int m = 0; m < NPB; ++m) {
        float h = s_phys[m*3+0] * w1v0 + s_phys[m*3+1] * w1v1 + s_phys[m*3+2] * w1v2 + b1v;
        s_h1[m * HH + j] = fmaxf(h, 0.0f);
    }
    __syncthreads();

    // layer 2
    float acc[NPB];
#pragma unroll
    for (int m = 0; m < NPB; ++m) acc[m] = 0.0f;
#pragma unroll 4
    for (int i4 = 0; i4 < HH / 4; ++i4) {
        const int i = i4 * 4;
        const float wv0 = w2[(i + 0) * HH + j];
        const float wv1 = w2[(i + 1) * HH + j];
        const float wv2 = w2[(i + 2) * HH + j];
        const float wv3 = w2[(i + 3) * HH + j];
#pragma unroll
        for (int m = 0; m < NPB; ++m) {
            const float4 h4 = *(const float4*)&s_h1[m * HH + i];
            acc[m] += h4.x * wv0 + h4.y * wv1 + h4.z * wv2 + h4.w * wv3;
        }
    }

    const float b2v = b2[j];
    const float w30 = w3[j * 2 + 0], w31 = w3[j * 2 + 1];
    const int wv = j >> 6;

    // layer 3 partials + wave reduction
#pragma unroll
    for (int m = 0; m < NPB; ++m) {
        const float h2 = fmaxf(acc[m] + b2v, 0.0f);
        float r0 = h2 * w30;
        float r1 = h2 * w31;
#pragma unroll
        for (int o = 32; o >= 1; o >>= 1) {
            r0 += __shfl_xor(r0, o);
            r1 += __shfl_xor(r1, o);
        }
        if ((j & 63) == 0) { s_red[wv][m][0] = r0; s_red[wv][m][1] = r1; }
    }
    __syncthreads();

    if (j < NPB * 2) {
        const int m = j >> 1, d = j & 1;
        float raw = s_red[0][m][d] + s_red[1][m][d] + s_red[2][m][d] + s_red[3][m][d] + b3[d];
        float p;
        if (d == 0) p = sigmoidf_(raw) * 0.25f + 0.005f;          // k
        else        p = sigmoidf_(raw - 3.0f) * 1.2f;             // xw
        s_kxw[m][d] = p;
    }
    __syncthreads();

    // IRF tail: node m = j>>5 (32 lanes/node), taps l and l+32
    {
        const int m = j >> 5, l = j & 31;
        const float k  = s_kxw[m][0];
        const float xw = s_kxw[m][1];
        const float delay = k * xw;
        const float tau   = fmaxf(k * (1.0f - xw), 0.5f * DTF);
        const float t0f = l * DTF, t1f = (l + 32) * DTF;
        float h0 = (t0f >= delay) ? __expf(-(t0f - delay) / tau) / tau : 0.0f;
        float h1 = (t1f >= delay) ? __expf(-(t1f - delay) / tau) / tau : 0.0f;
        float s = h0 + h1;
#pragma unroll
        for (int o = 16; o >= 1; o >>= 1) s += __shfl_xor(s, o);   // stays in 32-lane group
        const float inv = 1.0f / (s + 1e-8f);
        float* dst = irf + (size_t)(n0 + m) * WW;
        dst[l]      = h0 * inv;
        dst[l + 32] = h1 * inv;
    }
}

// ---------------- per-level routing conv, T-chunked, 1 wave/block ----------------
// out[n] = irf_n (x) (x[n] + sum_children out[c]); children of n: 4n+1..4n+4.
// Block = (node, batch, chunk). A-window [t0-64, t0+255] staged in LDS.
__global__ __launch_bounds__(64) void route_level(
    const float* __restrict__ x,
    const float* __restrict__ irf,
    float* __restrict__ out,
    int level_start)
{
    const int bid   = blockIdx.x;
    const int chunk = bid & 3;
    const int b     = (bid >> 2) & 1;
    const int n     = level_start + (bid >> 3);
    const int tid   = threadIdx.x;

    __shared__ __align__(16) float s_acc[WW + CHUNK];   // 320 floats

    const size_t rowb = ((size_t)b * NN + n) * TT;
    const int t0 = chunk * CHUNK;
    const int c0 = 4 * n + 1;

    // stage A window cooperatively: 80 float4 positions (p = tid, then tid+64 for tid<16)
    for (int p = tid; p < (WW + CHUNK) / 4; p += 64) {
        const int g = t0 - WW + 4 * p;                 // global t of this float4
        float4 v = make_float4(0.f, 0.f, 0.f, 0.f);
        if (g >= 0) {
            v = *(const float4*)&x[rowb + g];
#pragma unroll
            for (int e = 0; e < 4; ++e) {
                const int c = c0 + e;
                if (c < NN) {
                    const float4 u = *(const float4*)&out[((size_t)b * NN + c) * TT + g];
                    v.x += u.x; v.y += u.y; v.z += u.z; v.w += u.w;
                }
            }
        }
        *(float4*)&s_acc[4 * p] = v;
    }

    // rf via wave-uniform addresses -> scalar loads (SMEM path, off the LDS pipe)
    float rf[WW];
    const float* irp = irf + (size_t)n * WW;
#pragma unroll
    for (int i = 0; i < WW / 4; ++i) {
        const float4 f = *(const float4*)&irp[4 * i];
        rf[4*i+0] = f.x; rf[4*i+1] = f.y; rf[4*i+2] = f.z; rf[4*i+3] = f.w;
    }

    __syncthreads();

    const int base = tid * 4;
    float y[4] = {0.f, 0.f, 0.f, 0.f};
#pragma unroll
    for (int blk = 0; blk < 17; ++blk) {
        const int i0 = blk * 4 - 64;                       // -64 .. 0
        const float4 a = *(const float4*)&s_acc[base + blk * 4];
        const float ae[4] = {a.x, a.y, a.z, a.w};
#pragma unroll
        for (int e = 0; e < 4; ++e) {
            const int i = i0 + e;
#pragma unroll
            for (int jj = 0; jj < 4; ++jj) {
                const int w = jj - i;
                if (w >= 0 && w < WW) y[jj] += rf[w] * ae[e];
            }
        }
    }

    *(float4*)&out[rowb + t0 + base] = make_float4(y[0], y[1], y[2], y[3]);
}

extern "C" void kernel_launch(void* const* d_in, const int* in_sizes, int n_in,
                              void* d_out, int out_size, void* d_ws, size_t ws_size,
                              hipStream_t stream) {
    const float* x    = (const float*)d_in[0];
    const float* phys = (const float*)d_in[1];
    const float* w1   = (const float*)d_in[2];
    const float* b1   = (const float*)d_in[3];
    const float* w2   = (const float*)d_in[4];
    const float* b2   = (const float*)d_in[5];
    const float* w3   = (const float*)d_in[6];
    const float* b3   = (const float*)d_in[7];
    // d_in[8] = parent, d_in[9] = depth: fixed 4-ary heap tree

    float* out = (float*)d_out;
    float* irf = (float*)d_ws;   // N*64 floats = 2 MB

    mlp_kernel<<<NN / NPB, 256, 0, stream>>>(phys, w1, b1, w2, b2, w3, b3, irf);

    static const int starts[9] = {0, 1, 5, 21, 85, 341, 1365, 5461, 8192};
    for (int d = 7; d >= 0; --d) {
        const int s   = starts[d];
        const int cnt = starts[d + 1] - s;
        route_level<<<cnt * 2 * (TT / CHUNK), 64, 0, stream>>>(x, irf, out, s);
    }
}